// Round 1
// baseline (398.026 us; speedup 1.0000x reference)
//
#include <hip/hip_runtime.h>
#include <hip/hip_bf16.h>
#include <stdint.h>

typedef __hip_bfloat16 bf16s;                                    // storage type
typedef __bf16 bf16x8 __attribute__((ext_vector_type(8)));       // MFMA operand
typedef float  floatx4 __attribute__((ext_vector_type(4)));      // MFMA acc

#define BM 128
#define BN 128
#define BK 32

__device__ __forceinline__ void gload_lds16(const void* g, void* l) {
    auto* gp = reinterpret_cast<const __attribute__((address_space(1))) uint32_t*>(
        reinterpret_cast<uintptr_t>(g));
    auto* lp = reinterpret_cast<__attribute__((address_space(3))) uint32_t*>(
        reinterpret_cast<uintptr_t>(l));
    __builtin_amdgcn_global_load_lds(gp, lp, 16, 0, 0);
}

// ---------- x (f32) -> bf16, vectorized ----------
__global__ void cvt_f32_bf16(const float* __restrict__ x, bf16s* __restrict__ y, long n4) {
    long i = (long)blockIdx.x * blockDim.x + threadIdx.x;
    long stride = (long)gridDim.x * blockDim.x;
    for (; i < n4; i += stride) {
        float4 v = ((const float4*)x)[i];
        bf16s tmp[4];
        tmp[0] = __float2bfloat16(v.x);
        tmp[1] = __float2bfloat16(v.y);
        tmp[2] = __float2bfloat16(v.z);
        tmp[3] = __float2bfloat16(v.w);
        *(uint2*)&y[i * 4] = *(uint2*)tmp;
    }
}

// ---------- Wadj = W + lora_B @ lora_A, output bf16 ----------
__global__ void adjust_weight(const float* __restrict__ W, const float* __restrict__ lA,
                              const float* __restrict__ lB, bf16s* __restrict__ Wb,
                              int N, int Kd, int r) {
    long idx = (long)blockIdx.x * blockDim.x + threadIdx.x;
    int kq = Kd >> 2;
    long total = (long)N * kq;
    if (idx >= total) return;
    int n  = (int)(idx / kq);
    int k4 = (int)(idx - (long)n * kq) << 2;
    float4 w = *(const float4*)&W[(size_t)n * Kd + k4];
    float a0 = w.x, a1 = w.y, a2 = w.z, a3 = w.w;
    for (int j = 0; j < r; ++j) {
        float b = lB[n * r + j];
        float4 av = *(const float4*)&lA[(size_t)j * Kd + k4];
        a0 += b * av.x; a1 += b * av.y; a2 += b * av.z; a3 += b * av.w;
    }
    bf16s tmp[4];
    tmp[0] = __float2bfloat16(a0);
    tmp[1] = __float2bfloat16(a1);
    tmp[2] = __float2bfloat16(a2);
    tmp[3] = __float2bfloat16(a3);
    *(uint2*)&Wb[(size_t)n * Kd + k4] = *(uint2*)tmp;
}

// ---------- main GEMM: C[M,N] = A[M,K] @ B[N,K]^T + bias, m97 structure ----------
__global__ void gemm_bt_bias(const bf16s* __restrict__ A,   // [M,K] bf16
                             const bf16s* __restrict__ B,   // [N,K] bf16
                             const float* __restrict__ bias,
                             float* __restrict__ C,         // [M,N] f32
                             int M, int N, int K) {
    __shared__ __align__(16) bf16s As[BM][BK];
    __shared__ __align__(16) bf16s Bs[BN][BK];

    int nbn = N / BN;
    int nwg = gridDim.x;
    int bid = blockIdx.x;
    int swz = bid;
    if ((nwg & 7) == 0) swz = (bid & 7) * (nwg >> 3) + (bid >> 3);   // bijective XCD swizzle
    int bm = swz / nbn, bn = swz % nbn;

    int th   = threadIdx.x;
    int lane = th & 63;
    int wid  = th >> 6;
    int wr = wid >> 1, wc = wid & 1;   // 2x2 wave grid, 64x64 per wave

    int ld_row = th >> 2;              // 0..63
    int ld_col = (th & 3) * 8;         // k offset (elems)

    const bf16s* gA = A + (size_t)(bm * BM + ld_row) * K + ld_col;
    const bf16s* gB = B + (size_t)(bn * BN + ld_row) * K + ld_col;

    floatx4 acc[4][4];
#pragma unroll
    for (int m = 0; m < 4; ++m)
#pragma unroll
        for (int n = 0; n < 4; ++n)
            acc[m][n] = (floatx4){0.f, 0.f, 0.f, 0.f};

    const int lrow = lane & 15;
    const int lk   = (lane >> 4) * 8;

    for (int k0 = 0; k0 < K; k0 += BK) {
        gload_lds16(gA,                 &As[ld_row][ld_col]);
        gload_lds16(gA + (size_t)64 * K, &As[64 + ld_row][ld_col]);
        gload_lds16(gB,                 &Bs[ld_row][ld_col]);
        gload_lds16(gB + (size_t)64 * K, &Bs[64 + ld_row][ld_col]);
        gA += BK; gB += BK;
        __syncthreads();   // drains vmcnt before any wave reads LDS

        bf16x8 af[4], bfr[4];
#pragma unroll
        for (int m = 0; m < 4; ++m)
            af[m] = *(const bf16x8*)&As[wr * 64 + m * 16 + lrow][lk];
#pragma unroll
        for (int n = 0; n < 4; ++n)
            bfr[n] = *(const bf16x8*)&Bs[wc * 64 + n * 16 + lrow][lk];
#pragma unroll
        for (int m = 0; m < 4; ++m)
#pragma unroll
            for (int n = 0; n < 4; ++n)
                acc[m][n] = __builtin_amdgcn_mfma_f32_16x16x32_bf16(af[m], bfr[n], acc[m][n], 0, 0, 0);
        __syncthreads();   // before next stage overwrites LDS
    }

    // epilogue: C/D layout col = lane&15, row = (lane>>4)*4 + q   [verified m89/m91]
    int crow_base = bm * BM + wr * 64;
    int ccol_base = bn * BN + wc * 64;
#pragma unroll
    for (int n = 0; n < 4; ++n) {
        int col = ccol_base + n * 16 + (lane & 15);
        float bv = bias[col];
#pragma unroll
        for (int m = 0; m < 4; ++m) {
            int row0 = crow_base + m * 16 + (lane >> 4) * 4;
#pragma unroll
            for (int q = 0; q < 4; ++q)
                C[(size_t)(row0 + q) * N + col] = acc[m][n][q] + bv;
        }
    }
}

// ---------- fallback (f32, slow but correct) ----------
__global__ void xa_kernel(const float* __restrict__ x, const float* __restrict__ lA,
                          float* __restrict__ xa, long M, int K, int r) {
    long idx = (long)blockIdx.x * blockDim.x + threadIdx.x;
    long total = M * r;
    if (idx >= total) return;
    long m = idx / r; int j = (int)(idx % r);
    const float* xr = x + m * (long)K;
    const float* ar = lA + (size_t)j * K;
    float s = 0.f;
    for (int k = 0; k < K; k += 4) {
        float4 xv = *(const float4*)&xr[k];
        float4 av = *(const float4*)&ar[k];
        s += xv.x * av.x + xv.y * av.y + xv.z * av.z + xv.w * av.w;
    }
    xa[idx] = s;
}

__global__ void naive_out(const float* __restrict__ x, const float* __restrict__ W,
                          const float* __restrict__ bias, const float* __restrict__ xa,
                          const float* __restrict__ lB, float* __restrict__ out,
                          long M, int N, int K, int r) {
    long idx = (long)blockIdx.x * blockDim.x + threadIdx.x;
    long total = M * (long)N;
    if (idx >= total) return;
    long m = idx / N; int n = (int)(idx % N);
    const float* xr = x + m * (long)K;
    const float* wr = W + (size_t)n * K;
    float s = bias[n];
    for (int k = 0; k < K; k += 4) {
        float4 xv = *(const float4*)&xr[k];
        float4 wv = *(const float4*)&wr[k];
        s += xv.x * wv.x + xv.y * wv.y + xv.z * wv.z + xv.w * wv.w;
    }
    const float* xar = xa + m * r;
    const float* br  = lB + (size_t)n * r;
    for (int j = 0; j < r; ++j) s += xar[j] * br[j];
    out[idx] = s;
}

extern "C" void kernel_launch(void* const* d_in, const int* in_sizes, int n_in,
                              void* d_out, int out_size, void* d_ws, size_t ws_size,
                              hipStream_t stream) {
    const float* x    = (const float*)d_in[0];
    const float* W    = (const float*)d_in[1];
    const float* bias = (const float*)d_in[2];
    const float* lA   = (const float*)d_in[3];
    const float* lB   = (const float*)d_in[4];
    float* out = (float*)d_out;

    const int  N  = in_sizes[2];                  // d_out = 4096
    const int  Kd = in_sizes[1] / N;              // d_in  = 4096
    const int  r  = in_sizes[4] / N;              // 16
    const long M  = (long)in_sizes[0] / Kd;       // B*S   = 8192

    size_t xb_bytes = (size_t)M * Kd * sizeof(bf16s);
    size_t wb_bytes = (size_t)N * Kd * sizeof(bf16s);

    if (ws_size >= xb_bytes + wb_bytes &&
        (M % BM) == 0 && (N % BN) == 0 && (Kd % BK) == 0) {
        bf16s* xb = (bf16s*)d_ws;
        bf16s* wb = (bf16s*)((char*)d_ws + xb_bytes);

        long n4 = (long)M * Kd / 4;
        cvt_f32_bf16<<<2048, 256, 0, stream>>>(x, xb, n4);

        long total_w = (long)N * (Kd / 4);
        int blk_w = (int)((total_w + 255) / 256);
        adjust_weight<<<blk_w, 256, 0, stream>>>(W, lA, lB, wb, N, Kd, r);

        int grid = (int)(M / BM) * (N / BN);
        gemm_bt_bias<<<grid, 256, 0, stream>>>(xb, wb, bias, out, (int)M, N, Kd);
    } else {
        // f32 fallback: xa = x @ lA^T  (M x r), then naive out
        float* xa = (float*)d_ws;   // needs M*r*4 bytes = 512 KB
        long total_xa = M * (long)r;
        int blk_xa = (int)((total_xa + 255) / 256);
        xa_kernel<<<blk_xa, 256, 0, stream>>>(x, lA, xa, M, Kd, r);
        long total_o = M * (long)N;
        int blk_o = (int)((total_o + 255) / 256);
        naive_out<<<blk_o, 256, 0, stream>>>(x, W, bias, xa, lB, out, M, N, Kd, r);
    }
}

// Round 2
// 334.754 us; speedup vs baseline: 1.1890x; 1.1890x over previous
//
#include <hip/hip_runtime.h>
#include <hip/hip_bf16.h>
#include <stdint.h>

typedef __hip_bfloat16 bf16s;                                    // storage type
typedef __bf16 bf16x8 __attribute__((ext_vector_type(8)));       // MFMA operand
typedef float  floatx4 __attribute__((ext_vector_type(4)));      // MFMA acc

#define BM 256
#define BN 256
#define BK 32

__device__ __forceinline__ void gload_lds16(const void* g, void* l) {
    auto* gp = reinterpret_cast<const __attribute__((address_space(1))) uint32_t*>(
        reinterpret_cast<uintptr_t>(g));
    auto* lp = reinterpret_cast<__attribute__((address_space(3))) uint32_t*>(
        reinterpret_cast<uintptr_t>(l));
    __builtin_amdgcn_global_load_lds(gp, lp, 16, 0, 0);
}

// ---------- x (f32) -> bf16, vectorized ----------
__global__ void cvt_f32_bf16(const float* __restrict__ x, bf16s* __restrict__ y, long n4) {
    long i = (long)blockIdx.x * blockDim.x + threadIdx.x;
    long stride = (long)gridDim.x * blockDim.x;
    for (; i < n4; i += stride) {
        float4 v = ((const float4*)x)[i];
        bf16s tmp[4];
        tmp[0] = __float2bfloat16(v.x);
        tmp[1] = __float2bfloat16(v.y);
        tmp[2] = __float2bfloat16(v.z);
        tmp[3] = __float2bfloat16(v.w);
        *(uint2*)&y[i * 4] = *(uint2*)tmp;
    }
}

// ---------- Wadj = W + lora_B @ lora_A, output bf16 ----------
__global__ void adjust_weight(const float* __restrict__ W, const float* __restrict__ lA,
                              const float* __restrict__ lB, bf16s* __restrict__ Wb,
                              int N, int Kd, int r) {
    long idx = (long)blockIdx.x * blockDim.x + threadIdx.x;
    int kq = Kd >> 2;
    long total = (long)N * kq;
    if (idx >= total) return;
    int n  = (int)(idx / kq);
    int k4 = (int)(idx - (long)n * kq) << 2;
    float4 w = *(const float4*)&W[(size_t)n * Kd + k4];
    float a0 = w.x, a1 = w.y, a2 = w.z, a3 = w.w;
    for (int j = 0; j < r; ++j) {
        float b = lB[n * r + j];
        float4 av = *(const float4*)&lA[(size_t)j * Kd + k4];
        a0 += b * av.x; a1 += b * av.y; a2 += b * av.z; a3 += b * av.w;
    }
    bf16s tmp[4];
    tmp[0] = __float2bfloat16(a0);
    tmp[1] = __float2bfloat16(a1);
    tmp[2] = __float2bfloat16(a2);
    tmp[3] = __float2bfloat16(a3);
    *(uint2*)&Wb[(size_t)n * Kd + k4] = *(uint2*)tmp;
}

// ==========================================================================
// 256x256 tile, BK=32, 8 waves (2M x 4N), 4-deep LDS ring, counted vmcnt(8),
// 16B-granule XOR swizzle (both-sides), setprio around MFMA clusters.
// LDS: 4 bufs x (A 256x32 + B 256x32) bf16 = 128 KiB -> 1 block/CU.
// ==========================================================================

// stage one 128-row half (128 x 32 bf16 = 8KB) with pre-swizzled global src.
// LDS dest is linear (th*16B); source granule g is XORed so that a swizzled
// ds_read recovers the correct data (involution).
__device__ __forceinline__ void stage_half(const bf16s* __restrict__ gbase,
                                           bf16s* lbase, int th, int K, int k0) {
    int row = th >> 2;                          // 0..127
    int g   = (th & 3) ^ ((row >> 1) & 3);      // pre-swizzled source granule
    gload_lds16(gbase + (size_t)row * K + k0 + g * 8, lbase + th * 8);
}

// swizzled fragment read: row-major [256][32] bf16 with 16B granules XORed by
// (row>>1)&3. Makes each ds_read_b128 exactly 2-way per bank (free, m136).
__device__ __forceinline__ bf16x8 ld_frag(const bf16s* buf, int row, int kgran) {
    int g = kgran ^ ((row >> 1) & 3);
    return *(const bf16x8*)(buf + row * 32 + g * 8);
}

__global__ __launch_bounds__(512, 2)
void gemm_bt_bias_256(const bf16s* __restrict__ A,   // [M,K] bf16
                      const bf16s* __restrict__ B,   // [N,K] bf16
                      const float* __restrict__ bias,
                      float* __restrict__ C,         // [M,N] f32
                      int M, int N, int K) {
    __shared__ __align__(16) bf16s ldsA[4][BM * BK];
    __shared__ __align__(16) bf16s ldsB[4][BN * BK];

    const int nbn = N / BN;
    const int nwg = gridDim.x;
    int bid = blockIdx.x;
    int swz = bid;
    if ((nwg & 7) == 0) swz = (bid & 7) * (nwg >> 3) + (bid >> 3);   // bijective XCD swizzle
    const int bm = swz / nbn, bn = swz % nbn;

    const int th   = threadIdx.x;
    const int lane = th & 63;
    const int wid  = th >> 6;
    const int wm = wid >> 2;           // 0..1  -> 128-row slice
    const int wn = wid & 3;            // 0..3  -> 64-col slice

    const bf16s* gA = A + (size_t)(bm * BM) * K;
    const bf16s* gB = B + (size_t)(bn * BN) * K;

    const int NT = K / BK;

    floatx4 acc[8][4];
#pragma unroll
    for (int m = 0; m < 8; ++m)
#pragma unroll
        for (int n = 0; n < 4; ++n)
            acc[m][n] = (floatx4){0.f, 0.f, 0.f, 0.f};

    const int lr = lane & 15;
    const int kg = lane >> 4;          // 16B granule along K

    // ---- prologue: stage K-tiles 0,1,2 into ring bufs 0,1,2 (12 gloads) ----
#pragma unroll
    for (int pt = 0; pt < 3; ++pt) {
        int k0 = pt * BK;
        stage_half(gA,               &ldsA[pt][0],        th, K, k0);
        stage_half(gA + (size_t)128 * K, &ldsA[pt][128 * BK], th, K, k0);
        stage_half(gB,               &ldsB[pt][0],        th, K, k0);
        stage_half(gB + (size_t)128 * K, &ldsB[pt][128 * BK], th, K, k0);
    }
    asm volatile("s_waitcnt vmcnt(8)" ::: "memory");   // tile 0 landed
    __builtin_amdgcn_s_barrier();

    // ---- main loop: 1 barrier / K-tile, vmcnt(8) counted (never 0) ----
    for (int t = 0; t < NT; ++t) {
        const int cur = t & 3;
        const bf16s* Ab = &ldsA[cur][0];
        const bf16s* Bb = &ldsB[cur][0];

        // prefetch K-tile t+3 into ring buf (t+3)&3. Tail tiles re-stage the
        // last valid tile (dummy) so the vmcnt count stays uniform.
        {
            int tf  = t + 3;
            int buf = tf & 3;
            int ts  = tf < NT ? tf : NT - 1;
            int k0  = ts * BK;
            stage_half(gA,               &ldsA[buf][0],        th, K, k0);
            stage_half(gA + (size_t)128 * K, &ldsA[buf][128 * BK], th, K, k0);
            stage_half(gB,               &ldsB[buf][0],        th, K, k0);
            stage_half(gB + (size_t)128 * K, &ldsB[buf][128 * BK], th, K, k0);
        }

        // fragments (swizzled reads, conflict-free)
        bf16x8 bfr[4];
#pragma unroll
        for (int n = 0; n < 4; ++n)
            bfr[n] = ld_frag(Bb, wn * 64 + n * 16 + lr, kg);

        bf16x8 af[4];
#pragma unroll
        for (int m = 0; m < 4; ++m)
            af[m] = ld_frag(Ab, wm * 128 + m * 16 + lr, kg);

        __builtin_amdgcn_s_setprio(1);
#pragma unroll
        for (int m = 0; m < 4; ++m)
#pragma unroll
            for (int n = 0; n < 4; ++n)
                acc[m][n] = __builtin_amdgcn_mfma_f32_16x16x32_bf16(af[m], bfr[n], acc[m][n], 0, 0, 0);
        __builtin_amdgcn_s_setprio(0);

        bf16x8 af2[4];
#pragma unroll
        for (int m = 0; m < 4; ++m)
            af2[m] = ld_frag(Ab, wm * 128 + 64 + m * 16 + lr, kg);

        __builtin_amdgcn_s_setprio(1);
#pragma unroll
        for (int m = 0; m < 4; ++m)
#pragma unroll
            for (int n = 0; n < 4; ++n)
                acc[m + 4][n] = __builtin_amdgcn_mfma_f32_16x16x32_bf16(af2[m], bfr[n], acc[m + 4][n], 0, 0, 0);
        __builtin_amdgcn_s_setprio(0);

        // counted wait: tiles t+2, t+3 stay in flight across the barrier (T4)
        asm volatile("s_waitcnt vmcnt(8)" ::: "memory");
        __builtin_amdgcn_s_barrier();
    }

    // ---- epilogue: C/D layout col = lane&15, row = (lane>>4)*4 + q ----
    const int crow_base = bm * BM + wm * 128;
    const int ccol_base = bn * BN + wn * 64;
#pragma unroll
    for (int n = 0; n < 4; ++n) {
        int col = ccol_base + n * 16 + lr;
        float bv = bias[col];
#pragma unroll
        for (int m = 0; m < 8; ++m) {
            int row0 = crow_base + m * 16 + kg * 4;
#pragma unroll
            for (int q = 0; q < 4; ++q)
                C[(size_t)(row0 + q) * N + col] = acc[m][n][q] + bv;
        }
    }
}

// ---------- fallback (f32, slow but correct) ----------
__global__ void xa_kernel(const float* __restrict__ x, const float* __restrict__ lA,
                          float* __restrict__ xa, long M, int K, int r) {
    long idx = (long)blockIdx.x * blockDim.x + threadIdx.x;
    long total = M * r;
    if (idx >= total) return;
    long m = idx / r; int j = (int)(idx % r);
    const float* xr = x + m * (long)K;
    const float* ar = lA + (size_t)j * K;
    float s = 0.f;
    for (int k = 0; k < K; k += 4) {
        float4 xv = *(const float4*)&xr[k];
        float4 av = *(const float4*)&ar[k];
        s += xv.x * av.x + xv.y * av.y + xv.z * av.z + xv.w * av.w;
    }
    xa[idx] = s;
}

__global__ void naive_out(const float* __restrict__ x, const float* __restrict__ W,
                          const float* __restrict__ bias, const float* __restrict__ xa,
                          const float* __restrict__ lB, float* __restrict__ out,
                          long M, int N, int K, int r) {
    long idx = (long)blockIdx.x * blockDim.x + threadIdx.x;
    long total = M * (long)N;
    if (idx >= total) return;
    long m = idx / N; int n = (int)(idx % N);
    const float* xr = x + m * (long)K;
    const float* wr = W + (size_t)n * K;
    float s = bias[n];
    for (int k = 0; k < K; k += 4) {
        float4 xv = *(const float4*)&xr[k];
        float4 wv = *(const float4*)&wr[k];
        s += xv.x * wv.x + xv.y * wv.y + xv.z * wv.z + xv.w * wv.w;
    }
    const float* xar = xa + m * r;
    const float* br  = lB + (size_t)n * r;
    for (int j = 0; j < r; ++j) s += xar[j] * br[j];
    out[idx] = s;
}

extern "C" void kernel_launch(void* const* d_in, const int* in_sizes, int n_in,
                              void* d_out, int out_size, void* d_ws, size_t ws_size,
                              hipStream_t stream) {
    const float* x    = (const float*)d_in[0];
    const float* W    = (const float*)d_in[1];
    const float* bias = (const float*)d_in[2];
    const float* lA   = (const float*)d_in[3];
    const float* lB   = (const float*)d_in[4];
    float* out = (float*)d_out;

    const int  N  = in_sizes[2];                  // d_out = 4096
    const int  Kd = in_sizes[1] / N;              // d_in  = 4096
    const int  r  = in_sizes[4] / N;              // 16
    const long M  = (long)in_sizes[0] / Kd;       // B*S   = 8192

    size_t xb_bytes = (size_t)M * Kd * sizeof(bf16s);
    size_t wb_bytes = (size_t)N * Kd * sizeof(bf16s);

    if (ws_size >= xb_bytes + wb_bytes &&
        (M % BM) == 0 && (N % BN) == 0 && (Kd % BK) == 0 && (Kd / BK) >= 4) {
        bf16s* xb = (bf16s*)d_ws;
        bf16s* wb = (bf16s*)((char*)d_ws + xb_bytes);

        long n4 = (long)M * Kd / 4;
        cvt_f32_bf16<<<2048, 256, 0, stream>>>(x, xb, n4);

        long total_w = (long)N * (Kd / 4);
        int blk_w = (int)((total_w + 255) / 256);
        adjust_weight<<<blk_w, 256, 0, stream>>>(W, lA, lB, wb, N, Kd, r);

        int grid = (int)(M / BM) * (N / BN);
        gemm_bt_bias_256<<<grid, 512, 0, stream>>>(xb, wb, bias, out, (int)M, N, Kd);
    } else {
        // f32 fallback: xa = x @ lA^T  (M x r), then naive out
        float* xa = (float*)d_ws;   // needs M*r*4 bytes = 512 KB
        long total_xa = M * (long)r;
        int blk_xa = (int)((total_xa + 255) / 256);
        xa_kernel<<<blk_xa, 256, 0, stream>>>(x, lA, xa, M, Kd, r);
        long total_o = M * (long)N;
        int blk_o = (int)((total_o + 255) / 256);
        naive_out<<<blk_o, 256, 0, stream>>>(x, W, bias, xa, lB, out, M, N, Kd, r);
    }
}

// Round 4
// 321.279 us; speedup vs baseline: 1.2389x; 1.0419x over previous
//
#include <hip/hip_runtime.h>
#include <hip/hip_bf16.h>
#include <stdint.h>

typedef __hip_bfloat16 bf16s;                                    // storage type
typedef __bf16 bf16x8 __attribute__((ext_vector_type(8)));       // MFMA operand
typedef float  floatx4 __attribute__((ext_vector_type(4)));      // MFMA acc

#define BM 256
#define BN 256
#define BK 64

__device__ __forceinline__ void gload_lds16(const void* g, void* l) {
    auto* gp = reinterpret_cast<const __attribute__((address_space(1))) uint32_t*>(
        reinterpret_cast<uintptr_t>(g));
    auto* lp = reinterpret_cast<__attribute__((address_space(3))) uint32_t*>(
        reinterpret_cast<uintptr_t>(l));
    __builtin_amdgcn_global_load_lds(gp, lp, 16, 0, 0);
}

// ---------- x (f32) -> bf16, vectorized ----------
__global__ void cvt_f32_bf16(const float* __restrict__ x, bf16s* __restrict__ y, long n4) {
    long i = (long)blockIdx.x * blockDim.x + threadIdx.x;
    long stride = (long)gridDim.x * blockDim.x;
    for (; i < n4; i += stride) {
        float4 v = ((const float4*)x)[i];
        bf16s tmp[4];
        tmp[0] = __float2bfloat16(v.x);
        tmp[1] = __float2bfloat16(v.y);
        tmp[2] = __float2bfloat16(v.z);
        tmp[3] = __float2bfloat16(v.w);
        *(uint2*)&y[i * 4] = *(uint2*)tmp;
    }
}

// ---------- Wadj = W + lora_B @ lora_A, output bf16 ----------
__global__ void adjust_weight(const float* __restrict__ W, const float* __restrict__ lA,
                              const float* __restrict__ lB, bf16s* __restrict__ Wb,
                              int N, int Kd, int r) {
    long idx = (long)blockIdx.x * blockDim.x + threadIdx.x;
    int kq = Kd >> 2;
    long total = (long)N * kq;
    if (idx >= total) return;
    int n  = (int)(idx / kq);
    int k4 = (int)(idx - (long)n * kq) << 2;
    float4 w = *(const float4*)&W[(size_t)n * Kd + k4];
    float a0 = w.x, a1 = w.y, a2 = w.z, a3 = w.w;
    for (int j = 0; j < r; ++j) {
        float b = lB[n * r + j];
        float4 av = *(const float4*)&lA[(size_t)j * Kd + k4];
        a0 += b * av.x; a1 += b * av.y; a2 += b * av.z; a3 += b * av.w;
    }
    bf16s tmp[4];
    tmp[0] = __float2bfloat16(a0);
    tmp[1] = __float2bfloat16(a1);
    tmp[2] = __float2bfloat16(a2);
    tmp[3] = __float2bfloat16(a3);
    *(uint2*)&Wb[(size_t)n * Kd + k4] = *(uint2*)tmp;
}

// ==========================================================================
// 256x256 tile, BK=64, 8 waves (2M x 4N), 8-phase schedule:
// per K-tile 4 quadrant phases {ds_read subtile | stage half-tile -> barrier
// -> 16 MFMA -> counted vmcnt(4) -> barrier}. LDS 2-deep dbuf = 128 KiB.
// TAIL IS UNIFORM: every iteration issues all 8 gload_lds (last tiles re-stage
// the final K-tile into the dead buffer) so the counted vmcnt(4) waits retire
// exactly the half-tiles the next phase reads. Final vmcnt(0) drains LDS-DMA
// before s_endpgm.
// ==========================================================================
__global__ __launch_bounds__(512, 2)
void gemm_8phase(const bf16s* __restrict__ A,   // [M,K] bf16
                 const bf16s* __restrict__ B,   // [N,K] bf16
                 const float* __restrict__ bias,
                 float* __restrict__ C,         // [M,N] f32
                 int M, int N, int K) {
    __shared__ __align__(16) bf16s lds[2][2][BM * BK];   // [dbuf][A=0/B=1]

    const int nbn = N / BN;
    const int nwg = gridDim.x;
    int bid = blockIdx.x;
    int swz = bid;
    if ((nwg & 7) == 0) swz = (bid & 7) * (nwg >> 3) + (bid >> 3);   // XCD swizzle
    const int bm = swz / nbn, bn = swz % nbn;

    const int th   = threadIdx.x;
    const int lane = th & 63;
    const int wid  = th >> 6;
    const int wm = wid >> 2;           // 0..1 -> 128-row slice
    const int wn = wid & 3;            // 0..3 -> 64-col slice
    const int lr = lane & 15;
    const int kg = lane >> 4;          // 16B granule group along K

    const bf16s* gA = A + (size_t)(bm * BM) * K;
    const bf16s* gB = B + (size_t)(bn * BN) * K;
    const int NT = K / BK;

    floatx4 acc[8][4];
#pragma unroll
    for (int m = 0; m < 8; ++m)
#pragma unroll
        for (int n = 0; n < 4; ++n)
            acc[m][n] = (floatx4){0.f, 0.f, 0.f, 0.f};

    // ---- staging: half-tile = 128 LDS rows, 2 gload_lds per thread.
    // LDS slot s of row l holds source granule s ^ (l&7) (XOR swizzle, both
    // sides). A rows permuted (wm-major), B rows permuted (wn-major) so each
    // staged half is gload_lds-contiguous.
    const int trow = th >> 3;                       // 0..63 rows per G-load
    const int tgr  = (th & 7) ^ (trow & 7);         // pre-swizzled src granule

    auto stageA = [&](int dbuf, int mh, int k0) {
#pragma unroll
        for (int g = 0; g < 2; ++g) {
            int p = g * 128 + mh * 64 + trow;       // phys A row
            gload_lds16(gA + (size_t)p * K + k0 + tgr * 8,
                        &lds[dbuf][0][(mh * 128 + g * 64) * BK + th * 8]);
        }
    };
    auto stageB = [&](int dbuf, int nh, int k0) {
#pragma unroll
        for (int g = 0; g < 2; ++g) {
            int rest = g * 64 + trow;               // 0..127
            int p = (rest >> 5) * 64 + nh * 32 + (rest & 31);   // phys B row
            gload_lds16(gB + (size_t)p * K + k0 + tgr * 8,
                        &lds[dbuf][1][(nh * 128 + g * 64) * BK + th * 8]);
        }
    };

    // ---- fragment reads (swizzled; l&7 == lr&7 for all frags) ----
    auto ldA = [&](const bf16s* base, int mh, int mp, int kk) -> bf16x8 {
        int l = mh * 128 + wm * 64 + mp * 16 + lr;
        int c = ((kk << 2) | kg) ^ (lr & 7);
        return *(const bf16x8*)(base + l * BK + c * 8);
    };
    auto ldB = [&](const bf16s* base, int nh, int np, int kk) -> bf16x8 {
        int l = nh * 128 + wn * 32 + np * 16 + lr;
        int c = ((kk << 2) | kg) ^ (lr & 7);
        return *(const bf16x8*)(base + l * BK + c * 8);
    };

    // ---- prologue: stage tile 0 fully; wait first 2 halves; enter loop ----
    stageA(0, 0, 0);
    stageB(0, 0, 0);
    stageB(0, 1, 0);
    stageA(0, 1, 0);
    asm volatile("s_waitcnt vmcnt(4)" ::: "memory");
    asm volatile("s_barrier" ::: "memory");

    for (int t = 0; t < NT; ++t) {
        const bf16s* Ab = &lds[t & 1][0][0];
        const bf16s* Bb = &lds[t & 1][1][0];
        const int nb = (t + 1) & 1;
        // UNIFORM TAIL: clamp source k to the last tile; always issue 8 loads
        // so per-wave vmcnt counts stay exact in every iteration.
        const int k1 = ((t + 1 < NT) ? (t + 1) : (NT - 1)) * BK;

        bf16x8 af[4][2], bfr[2][2][2];

        // ================= P1: quadrant (mh0, nh0) =================
#pragma unroll
        for (int mp = 0; mp < 4; ++mp)
#pragma unroll
            for (int kk = 0; kk < 2; ++kk)
                af[mp][kk] = ldA(Ab, 0, mp, kk);
#pragma unroll
        for (int np = 0; np < 2; ++np)
#pragma unroll
            for (int kk = 0; kk < 2; ++kk)
                bfr[0][np][kk] = ldB(Bb, 0, np, kk);
        stageA(nb, 0, k1);
        asm volatile("s_barrier" ::: "memory");
        __builtin_amdgcn_s_setprio(1);
#pragma unroll
        for (int mp = 0; mp < 4; ++mp)
#pragma unroll
            for (int np = 0; np < 2; ++np)
#pragma unroll
                for (int kk = 0; kk < 2; ++kk)
                    acc[mp][np] = __builtin_amdgcn_mfma_f32_16x16x32_bf16(
                        af[mp][kk], bfr[0][np][kk], acc[mp][np], 0, 0, 0);
        __builtin_amdgcn_s_setprio(0);
        asm volatile("s_waitcnt vmcnt(4)" ::: "memory");   // B-nh1(t) landed
        asm volatile("s_barrier" ::: "memory");

        // ================= P2: quadrant (mh0, nh1) =================
#pragma unroll
        for (int np = 0; np < 2; ++np)
#pragma unroll
            for (int kk = 0; kk < 2; ++kk)
                bfr[1][np][kk] = ldB(Bb, 1, np, kk);
        stageB(nb, 0, k1);
        asm volatile("s_barrier" ::: "memory");
        __builtin_amdgcn_s_setprio(1);
#pragma unroll
        for (int mp = 0; mp < 4; ++mp)
#pragma unroll
            for (int np = 0; np < 2; ++np)
#pragma unroll
                for (int kk = 0; kk < 2; ++kk)
                    acc[mp][2 + np] = __builtin_amdgcn_mfma_f32_16x16x32_bf16(
                        af[mp][kk], bfr[1][np][kk], acc[mp][2 + np], 0, 0, 0);
        __builtin_amdgcn_s_setprio(0);
        asm volatile("s_waitcnt vmcnt(4)" ::: "memory");   // A-mh1(t) landed
        asm volatile("s_barrier" ::: "memory");

        // ================= P3: quadrant (mh1, nh1) =================
#pragma unroll
        for (int mp = 0; mp < 4; ++mp)
#pragma unroll
            for (int kk = 0; kk < 2; ++kk)
                af[mp][kk] = ldA(Ab, 1, mp, kk);
        stageB(nb, 1, k1);
        asm volatile("s_barrier" ::: "memory");
        __builtin_amdgcn_s_setprio(1);
#pragma unroll
        for (int mp = 0; mp < 4; ++mp)
#pragma unroll
            for (int np = 0; np < 2; ++np)
#pragma unroll
                for (int kk = 0; kk < 2; ++kk)
                    acc[4 + mp][2 + np] = __builtin_amdgcn_mfma_f32_16x16x32_bf16(
                        af[mp][kk], bfr[1][np][kk], acc[4 + mp][2 + np], 0, 0, 0);
        __builtin_amdgcn_s_setprio(0);
        asm volatile("s_barrier" ::: "memory");            // no vmcnt (P4 reads regs only)

        // ================= P4: quadrant (mh1, nh0) =================
        stageA(nb, 1, k1);
        asm volatile("s_barrier" ::: "memory");
        __builtin_amdgcn_s_setprio(1);
#pragma unroll
        for (int mp = 0; mp < 4; ++mp)
#pragma unroll
            for (int np = 0; np < 2; ++np)
#pragma unroll
                for (int kk = 0; kk < 2; ++kk)
                    acc[4 + mp][np] = __builtin_amdgcn_mfma_f32_16x16x32_bf16(
                        af[mp][kk], bfr[0][np][kk], acc[4 + mp][np], 0, 0, 0);
        __builtin_amdgcn_s_setprio(0);
        asm volatile("s_waitcnt vmcnt(4)" ::: "memory");   // A-mh0,B-nh0(t+1) landed
        asm volatile("s_barrier" ::: "memory");
    }

    // drain our own outstanding LDS-DMA before s_endpgm (LDS is freed at exit)
    asm volatile("s_waitcnt vmcnt(0)" ::: "memory");

    // ---- epilogue: C/D layout col = lane&15, row = (lane>>4)*4 + q ----
    const int crow = bm * BM + wm * 128;
    const int ccol = bn * BN + wn * 64;
#pragma unroll
    for (int n = 0; n < 4; ++n) {
        int col = ccol + n * 16 + lr;
        float bv = bias[col];
#pragma unroll
        for (int m = 0; m < 8; ++m) {
            int row0 = crow + m * 16 + kg * 4;
#pragma unroll
            for (int q = 0; q < 4; ++q)
                C[(size_t)(row0 + q) * N + col] = acc[m][n][q] + bv;
        }
    }
}

// ---------- fallback (f32, slow but correct) ----------
__global__ void xa_kernel(const float* __restrict__ x, const float* __restrict__ lA,
                          float* __restrict__ xa, long M, int K, int r) {
    long idx = (long)blockIdx.x * blockDim.x + threadIdx.x;
    long total = M * r;
    if (idx >= total) return;
    long m = idx / r; int j = (int)(idx % r);
    const float* xr = x + m * (long)K;
    const float* ar = lA + (size_t)j * K;
    float s = 0.f;
    for (int k = 0; k < K; k += 4) {
        float4 xv = *(const float4*)&xr[k];
        float4 av = *(const float4*)&ar[k];
        s += xv.x * av.x + xv.y * av.y + xv.z * av.z + xv.w * av.w;
    }
    xa[idx] = s;
}

__global__ void naive_out(const float* __restrict__ x, const float* __restrict__ W,
                          const float* __restrict__ bias, const float* __restrict__ xa,
                          const float* __restrict__ lB, float* __restrict__ out,
                          long M, int N, int K, int r) {
    long idx = (long)blockIdx.x * blockDim.x + threadIdx.x;
    long total = M * (long)N;
    if (idx >= total) return;
    long m = idx / N; int n = (int)(idx % N);
    const float* xr = x + m * (long)K;
    const float* wr = W + (size_t)n * K;
    float s = bias[n];
    for (int k = 0; k < K; k += 4) {
        float4 xv = *(const float4*)&xr[k];
        float4 wv = *(const float4*)&wr[k];
        s += xv.x * wv.x + xv.y * wv.y + xv.z * wv.z + xv.w * wv.w;
    }
    const float* xar = xa + m * r;
    const float* br  = lB + (size_t)n * r;
    for (int j = 0; j < r; ++j) s += xar[j] * br[j];
    out[idx] = s;
}

extern "C" void kernel_launch(void* const* d_in, const int* in_sizes, int n_in,
                              void* d_out, int out_size, void* d_ws, size_t ws_size,
                              hipStream_t stream) {
    const float* x    = (const float*)d_in[0];
    const float* W    = (const float*)d_in[1];
    const float* bias = (const float*)d_in[2];
    const float* lA   = (const float*)d_in[3];
    const float* lB   = (const float*)d_in[4];
    float* out = (float*)d_out;

    const int  N  = in_sizes[2];                  // d_out = 4096
    const int  Kd = in_sizes[1] / N;              // d_in  = 4096
    const int  r  = in_sizes[4] / N;              // 16
    const long M  = (long)in_sizes[0] / Kd;       // B*S   = 8192

    size_t xb_bytes = (size_t)M * Kd * sizeof(bf16s);
    size_t wb_bytes = (size_t)N * Kd * sizeof(bf16s);

    if (ws_size >= xb_bytes + wb_bytes &&
        (M % BM) == 0 && (N % BN) == 0 && (Kd % BK) == 0 && (Kd / BK) >= 2) {
        bf16s* xb = (bf16s*)d_ws;
        bf16s* wb = (bf16s*)((char*)d_ws + xb_bytes);

        long n4 = (long)M * Kd / 4;
        cvt_f32_bf16<<<2048, 256, 0, stream>>>(x, xb, n4);

        long total_w = (long)N * (Kd / 4);
        int blk_w = (int)((total_w + 255) / 256);
        adjust_weight<<<blk_w, 256, 0, stream>>>(W, lA, lB, wb, N, Kd, r);

        int grid = (int)(M / BM) * (N / BN);
        gemm_8phase<<<grid, 512, 0, stream>>>(xb, wb, bias, out, (int)M, N, Kd);
    } else {
        // f32 fallback: xa = x @ lA^T  (M x r), then naive out
        float* xa = (float*)d_ws;   // needs M*r*4 bytes = 512 KB
        long total_xa = M * (long)r;
        int blk_xa = (int)((total_xa + 255) / 256);
        xa_kernel<<<blk_xa, 256, 0, stream>>>(x, lA, xa, M, Kd, r);
        long total_o = M * (long)N;
        int blk_o = (int)((total_o + 255) / 256);
        naive_out<<<blk_o, 256, 0, stream>>>(x, W, bias, xa, lB, out, M, N, Kd, r);
    }
}